// Round 4
// baseline (721.419 us; speedup 1.0000x reference)
//
#include <hip/hip_runtime.h>
#include <float.h>

// Problem constants
#define N_PTS    32768       // 8*16*16*16 spatial positions
#define N_CODES  2048
#define DIM      256
#define S_STRIDE 4096        // d*h*w stride of channel dim in z (floats)
#define B_STRIDE 1048576     // per-batch stride in z (256*4096 floats)
#define N_ELEM   8388608     // total z elements

// ws layout (bytes)
#define WS_LOSS   0          // float
#define WS_E2     16         // float[2048]
#define WS_Z2     8208       // float[32768]
#define WS_IDX    139280     // int[32768]   (end: 270352)

__global__ void init_kernel(float* loss) {
    if (threadIdx.x == 0) { *loss = 0.f; }
}

// numpy FLOAT_pairwise_sum emulation for n=256:
//   n>128 -> pw(a,128)+pw(a+128,128); each 128-block: 8 accumulators
//   r[j] = x[j]; 15 rounds r[j]+=x[8t+j]; combine ((r0+r1)+(r2+r3))+((r4+r5)+(r6+r7)).
// x[i] = fl32(v_i * v_i).  __f*_rn intrinsics block -ffp-contract=fast rebits.

// z2[n] = np-pairwise sum of z_flat[n][:]^2.  z_flat[n][c] = z[b*B_STRIDE + c*S_STRIDE + s].
__global__ void z2_kernel(const float* __restrict__ z, float* __restrict__ z2) {
    const int n = blockIdx.x * 256 + threadIdx.x;
    const int b = n >> 12, s = n & 4095;
    const float* base = z + (size_t)b * B_STRIDE + s;
    float half[2];
    #pragma unroll
    for (int h = 0; h < 2; ++h) {
        float r[8];
        #pragma unroll
        for (int j = 0; j < 8; ++j) {
            const float v = base[(size_t)(h * 128 + j) * S_STRIDE];
            r[j] = __fmul_rn(v, v);
        }
        for (int t = 8; t < 128; t += 8) {
            #pragma unroll
            for (int j = 0; j < 8; ++j) {
                const float v = base[(size_t)(h * 128 + t + j) * S_STRIDE];
                r[j] = __fadd_rn(r[j], __fmul_rn(v, v));
            }
        }
        half[h] = __fadd_rn(__fadd_rn(__fadd_rn(r[0], r[1]), __fadd_rn(r[2], r[3])),
                            __fadd_rn(__fadd_rn(r[4], r[5]), __fadd_rn(r[6], r[7])));
    }
    z2[n] = __fadd_rn(half[0], half[1]);
}

// e2[k] = np-pairwise sum of emb[k][:]^2 (contiguous).
__global__ void e2_kernel(const float* __restrict__ emb, float* __restrict__ e2) {
    const int k = blockIdx.x * 256 + threadIdx.x;
    const float* base = emb + (size_t)k * DIM;
    float half[2];
    #pragma unroll
    for (int h = 0; h < 2; ++h) {
        float r[8];
        #pragma unroll
        for (int j = 0; j < 8; ++j) {
            const float v = base[h * 128 + j];
            r[j] = __fmul_rn(v, v);
        }
        for (int t = 8; t < 128; t += 8) {
            #pragma unroll
            for (int j = 0; j < 8; ++j) {
                const float v = base[h * 128 + t + j];
                r[j] = __fadd_rn(r[j], __fmul_rn(v, v));
            }
        }
        half[h] = __fadd_rn(__fadd_rn(__fadd_rn(r[0], r[1]), __fadd_rn(r[2], r[3])),
                            __fadd_rn(__fadd_rn(r[4], r[5]), __fadd_rn(r[6], r[7])));
    }
    e2[k] = __fadd_rn(half[0], half[1]);
}

// Fused distance-GEMM + argmin, emulating np fp32 semantics:
//   dot[n,k] = single fp32 fma chain over c=0..255 ascending (matches sgemm K-block)
//   s[n,k]   = fl32( fl32(z2[n] + e2[k]) - 2*dot )
//   argmin with first-index tie-break  ==  np.argmin.
__global__ __launch_bounds__(256, 2) void argmin_kernel(
    const float* __restrict__ z, const float* __restrict__ emb,
    const float* __restrict__ e2, const float* __restrict__ z2,
    int* __restrict__ idxm, float* __restrict__ out_idx)
{
    __shared__ float zt[DIM * 64];   // [c][p] 64 KB
    __shared__ float et[64 * 64];    // [k][code] 16 KB
    const int tid = threadIdx.x;
    const int n0 = blockIdx.x * 64;
    const int b = n0 >> 12;
    const int s0 = n0 & 4095;

    // Stage z tile: zt[c][p] = z_flat[n0+p][c] = z[b][c][s0+p]
    {
        const int tq = tid & 15, cg = tid >> 4;
        for (int c = cg; c < DIM; c += 16) {
            const float4 u = *reinterpret_cast<const float4*>(
                z + (size_t)b * B_STRIDE + (size_t)c * S_STRIDE + s0 + tq * 4);
            float* d = &zt[c * 64 + tq * 4];
            d[0] = u.x; d[1] = u.y; d[2] = u.z; d[3] = u.w;
        }
    }

    const int px = tid >> 4;   // point group: points px*4+i
    const int cx = tid & 15;   // code group within tile: codes cx*4+j
    float z2p[4];
    #pragma unroll
    for (int i = 0; i < 4; i++) z2p[i] = z2[n0 + px * 4 + i];
    float m1[4]; int bi[4];
    #pragma unroll
    for (int i = 0; i < 4; i++) { m1[i] = FLT_MAX; bi[i] = 0; }

    for (int ct = 0; ct < N_CODES / 64; ++ct) {
        float acc[4][4];
        #pragma unroll
        for (int i = 0; i < 4; i++)
            #pragma unroll
            for (int j = 0; j < 4; j++) acc[i][j] = 0.f;

        for (int kc = 0; kc < 4; ++kc) {
            __syncthreads();
            {   // stage emb chunk transposed: et[k][code] = emb[ct*64+code][kc*64+k]
                const int er = tid >> 2, kq = tid & 3;
                const float* src = emb + (size_t)(ct * 64 + er) * DIM + kc * 64 + kq * 16;
                const float4 a0 = *reinterpret_cast<const float4*>(src);
                const float4 a1 = *reinterpret_cast<const float4*>(src + 4);
                const float4 a2 = *reinterpret_cast<const float4*>(src + 8);
                const float4 a3 = *reinterpret_cast<const float4*>(src + 12);
                const float v[16] = {a0.x, a0.y, a0.z, a0.w, a1.x, a1.y, a1.z, a1.w,
                                     a2.x, a2.y, a2.z, a2.w, a3.x, a3.y, a3.z, a3.w};
                #pragma unroll
                for (int j = 0; j < 16; j++) et[(kq * 16 + j) * 64 + er] = v[j];
            }
            __syncthreads();
            // channel c = kc*64+k ascends 0..255 across kc: exact k-ascending fma chain
            #pragma unroll 4
            for (int k = 0; k < 64; k++) {
                const float4 zv = *reinterpret_cast<const float4*>(&zt[(kc * 64 + k) * 64 + px * 4]);
                const float4 ev = *reinterpret_cast<const float4*>(&et[k * 64 + cx * 4]);
                const float zr[4] = {zv.x, zv.y, zv.z, zv.w};
                const float er2[4] = {ev.x, ev.y, ev.z, ev.w};
                #pragma unroll
                for (int i = 0; i < 4; i++)
                    #pragma unroll
                    for (int j = 0; j < 4; j++)
                        acc[i][j] = fmaf(zr[i], er2[j], acc[i][j]);
            }
        }
        // np-exact epilogue: s = fl(fl(z2 + e2) - 2*dot)
        const int cbase = ct * 64 + cx * 4;
        const float4 e2v = *reinterpret_cast<const float4*>(&e2[cbase]);
        const float e2a[4] = {e2v.x, e2v.y, e2v.z, e2v.w};
        #pragma unroll
        for (int i = 0; i < 4; i++) {
            #pragma unroll
            for (int j = 0; j < 4; j++) {
                const float A = __fadd_rn(z2p[i], e2a[j]);
                const float s = __fsub_rn(A, __fmul_rn(2.0f, acc[i][j]));
                if (s < m1[i]) { m1[i] = s; bi[i] = cbase + j; }   // strict < : first index wins
            }
        }
    }

    // reduce (min, first-idx) across the 16 cx lanes (lane bits 0..3)
    #pragma unroll
    for (int off = 1; off < 16; off <<= 1) {
        #pragma unroll
        for (int i = 0; i < 4; i++) {
            const float om1 = __shfl_xor(m1[i], off);
            const int obi = __shfl_xor(bi[i], off);
            if (om1 < m1[i] || (om1 == m1[i] && obi < bi[i])) { m1[i] = om1; bi[i] = obi; }
        }
    }
    if (cx == 0) {
        #pragma unroll
        for (int i = 0; i < 4; i++) {
            const int n = n0 + px * 4 + i;
            idxm[n] = bi[i];
            out_idx[n] = (float)bi[i];
        }
    }
}

// Gather z_q (faithful misaligned reshape), write fp32 z_q_st, fused loss accumulation.
__global__ void gather_loss_kernel(const float* __restrict__ z, const float* __restrict__ emb,
                                   const int* __restrict__ idxm, float* __restrict__ outf,
                                   float* __restrict__ loss)
{
    const int gid = blockIdx.x * 256 + threadIdx.x;     // 8192 blocks * 256 thr * 4 elems
    const size_t m0 = (size_t)gid * 4;
    const int row = (int)(m0 >> 8), col = (int)(m0 & 255);
    const int id = idxm[row];
    const float4 q = *reinterpret_cast<const float4*>(emb + (size_t)id * DIM + col);
    const float4 zv = *reinterpret_cast<const float4*>(z + m0);
    *reinterpret_cast<float4*>(outf + m0) = q;          // z_q_st == z_q in value
    const float d0 = q.x - zv.x, d1 = q.y - zv.y, d2 = q.z - zv.z, d3 = q.w - zv.w;
    float accl = d0 * d0 + d1 * d1 + d2 * d2 + d3 * d3;
    #pragma unroll
    for (int off = 32; off > 0; off >>= 1) accl += __shfl_xor(accl, off);
    __shared__ float part[4];
    const int lane = threadIdx.x & 63, w64 = threadIdx.x >> 6;
    if (lane == 0) part[w64] = accl;
    __syncthreads();
    if (threadIdx.x == 0) atomicAdd(loss, part[0] + part[1] + part[2] + part[3]);
}

__global__ void finalize_kernel(const float* __restrict__ loss, float* __restrict__ out_loss) {
    if (threadIdx.x == 0)
        *out_loss = loss[0] * 1.25f / (float)N_ELEM;     // (1+BETA)*mean
}

extern "C" void kernel_launch(void* const* d_in, const int* in_sizes, int n_in,
                              void* d_out, int out_size, void* d_ws, size_t ws_size,
                              hipStream_t stream) {
    const float* z = (const float*)d_in[0];
    const float* emb = (const float*)d_in[1];
    char* ws = (char*)d_ws;
    float* loss = (float*)(ws + WS_LOSS);
    float* e2 = (float*)(ws + WS_E2);
    float* z2 = (float*)(ws + WS_Z2);
    int* idxm = (int*)(ws + WS_IDX);
    float* outf = (float*)d_out;                         // fp32 outputs, concatenated in return order
    float* out_loss = outf + N_ELEM;                     // [8388608]
    float* out_idx = outf + N_ELEM + 1;                  // [8388609 ..]

    init_kernel<<<1, 64, 0, stream>>>(loss);
    z2_kernel<<<N_PTS / 256, 256, 0, stream>>>(z, z2);
    e2_kernel<<<N_CODES / 256, 256, 0, stream>>>(emb, e2);
    argmin_kernel<<<N_PTS / 64, 256, 0, stream>>>(z, emb, e2, z2, idxm, out_idx);
    gather_loss_kernel<<<N_ELEM / 1024, 256, 0, stream>>>(z, emb, idxm, outf, loss);
    finalize_kernel<<<1, 64, 0, stream>>>(loss, out_loss);
}